// Round 9
// baseline (45.214 us; speedup 1.0000x reference)
//
#include <hip/hip_runtime.h>

typedef _Float16 f16;
typedef __attribute__((ext_vector_type(8))) _Float16 f16x8;
typedef __attribute__((ext_vector_type(4))) float f32x4;

#define HWB 16384

// K layout (both GEMMs): k = kk*64 + c, 18 k-steps of 32 (ch-half in {0,1}).
// A-frag packs: lane l of k-step t, M-tile m holds W[o = m*16 + (l&15)]
//               [c = (t&1)*32 + (l>>4)*8 + j], kk = t>>1.
// wdef_ap: [t(18)][m(4)][lane(64)][j(8)] f16 = 73728 B
// woff_ap: [t(18)][m(2)][lane(64)][j(8)] f16 = 36864 B (o>=18 zero)

__device__ __forceinline__ void prep_elem(int i,
                                          const float* __restrict__ w_off,
                                          const float* __restrict__ w_def,
                                          f16* __restrict__ wdef_ap,
                                          f16* __restrict__ woff_ap) {
    if (i < 36864) {
        int j = i & 7, l = (i >> 3) & 63, m = (i >> 9) & 3, t = i >> 11;
        int kk = t >> 1, ch = t & 1;
        int o = m * 16 + (l & 15);
        int c = ch * 32 + (l >> 4) * 8 + j;
        wdef_ap[i] = (f16)w_def[o * 576 + c * 9 + kk];
    } else if (i < 55296) {
        int i2 = i - 36864;
        int j = i2 & 7, l = (i2 >> 3) & 63, m = (i2 >> 9) & 1, t = i2 >> 10;
        int kk = t >> 1, ch = t & 1;
        int o = m * 16 + (l & 15);
        int c = ch * 32 + (l >> 4) * 8 + j;
        woff_ap[i2] = (f16)((o < 18) ? w_off[o * 576 + c * 9 + kk] : 0.f);
    }
}

__global__ void k_prep(const float* __restrict__ w_off,
                       const float* __restrict__ w_def,
                       f16* __restrict__ wdef_ap,
                       f16* __restrict__ woff_ap) {
    prep_elem(blockIdx.x * 256 + threadIdx.x, w_off, w_def, wdef_ap, woff_ap);
}

// NCHW f32 -> NHWC f16 for all 4 batches, plus weight prep (merged launch).
__global__ void k_xprep(const float* __restrict__ x, f16* __restrict__ xt,
                        const float* __restrict__ w_off,
                        const float* __restrict__ w_def,
                        f16* __restrict__ wdef_ap,
                        f16* __restrict__ woff_ap) {
    int p = blockIdx.x * 256 + threadIdx.x;
    prep_elem(p, w_off, w_def, wdef_ap, woff_ap);
    int b = p >> 14, hw = p & 16383;
    const float* xb = x + (size_t)b * 64 * HWB + hw;
    f16x8 r[8];
    #pragma unroll
    for (int c = 0; c < 64; ++c) r[c >> 3][c & 7] = (f16)xb[(size_t)c * HWB];
    f16* ob = xt + (size_t)p * 64;
    #pragma unroll
    for (int q = 0; q < 8; ++q) *(f16x8*)(ob + q * 8) = r[q];
}

// NCHW f32 (slice) -> NHWC f16 (fallback path, per batch).
__global__ void k_xpose(const float* __restrict__ x, f16* __restrict__ xt) {
    int p = blockIdx.x * 256 + threadIdx.x;
    const float* xb = x + p;
    f16x8 r[8];
    #pragma unroll
    for (int c = 0; c < 64; ++c) r[c >> 3][c & 7] = (f16)xb[(size_t)c * HWB];
    f16* ob = xt + (size_t)p * 64;
    #pragma unroll
    for (int q = 0; q < 8; ++q) *(f16x8*)(ob + q * 8) = r[q];
}

// Block: 256 thr = 4 waves = 2 px-groups(32 px, nt=2 tiles) x 2 ch-halves.
// 64 px per block. 6-row x-band in LDS (hardtanh |off|<=1 -> rows h-2..h+3,
// cells s-2..s+66); chunk XOR swizzle (cc = gg ^ (cell&7)) -> ~conflict-free
// b128 reads. Phase 0 (18-channel offset conv) computed redundantly by both
// ch-half waves (saves the reduction buffer + a barrier; fits 64KB LDS).
// Phase 1 splits K across ch-half waves; partials combined via red1 (aliases
// the band, dead by then). A-fragments feed 2 MFMAs each (nt=2).
__launch_bounds__(256, 4)
__global__ void k_fused(const f16* __restrict__ xt,      // NHWC f16 slice
                        const f16* __restrict__ woff_ap,
                        const float* __restrict__ b_off,
                        const f16* __restrict__ wdef_ap,
                        const float* __restrict__ b_def,
                        float* __restrict__ out, int bstart) {
    __shared__ __align__(16) char band[6 * 69 * 128];    // 52992 B
    __shared__ float offsm[18 * 65];                     // 4680 B
    float* red1 = (float*)band;                          // 64*65*4 B alias

    int nwg = gridDim.x;
    int bid = blockIdx.x;
    int sb = (bid & 7) * (nwg >> 3) + (bid >> 3);        // bijective XCD swizzle
    int bl = sb >> 8, h = (sb >> 1) & 127, shalf = sb & 1;
    int b = bstart + bl;
    int s = shalf * 64;                                  // block px start
    int tid = threadIdx.x;
    int lane = tid & 63, wv = tid >> 6;
    int pxg = wv & 1, chh = wv >> 1;
    int l15 = lane & 15, g = lane >> 4;

    const f16* xb = xt + (size_t)bl * HWB * 64;

    // ---------------- stage 6-row band ----------------
    for (int i = tid; i < 6 * 69 * 8; i += 256) {
        int gg = i & 7, cell = (i >> 3) % 69, r = (i >> 3) / 69;
        int y = min(max(h - 2 + r, 0), 127);
        int xg = min(max(s - 2 + cell, 0), 127);
        f16x8 v = *(const f16x8*)(xb + (size_t)((y * 128 + xg) * 64 + gg * 8));
        int cc = gg ^ (cell & 7);
        *(f16x8*)(band + (r * 69 + cell) * 128 + cc * 16) = v;
    }
    __syncthreads();

    // ---------------- phase 0: offset conv, full K per wave ----------------
    f32x4 oacc[2][2];                                    // [nt][m]
    {
        f32x4 z = {0.f, 0.f, 0.f, 0.f};
        oacc[0][0] = z; oacc[0][1] = z; oacc[1][0] = z; oacc[1][1] = z;
    }
    f16x8 zb = {};
    #pragma unroll
    for (int kk = 0; kk < 9; ++kk) {
        int ky = kk / 3 - 1, kx = kk - (kk / 3) * 3 - 1;
        #pragma unroll
        for (int hf = 0; hf < 2; ++hf) {                 // ch-half
            int t = kk * 2 + hf;
            unsigned co2 = (unsigned)((hf * 4 + g) * 16);
            f16x8 Bv[2];
            #pragma unroll
            for (int nt = 0; nt < 2; ++nt) {
                int pxln = pxg * 32 + nt * 16 + l15;
                int yy = h + ky, xx = s + pxln + kx;
                bool valid = ((unsigned)yy < 128u) && ((unsigned)xx < 128u);
                int ry = min(max(yy, 0), 127) - (h - 2);
                int cx = min(max(xx, 0), 127) - (s - 2);
                f16x8 B = *(const f16x8*)(band + (ry * 69 + cx) * 128 +
                                          (co2 ^ (((unsigned)cx & 7u) << 4)));
                Bv[nt] = valid ? B : zb;
            }
            #pragma unroll
            for (int m = 0; m < 2; ++m) {
                f16x8 A = *(const f16x8*)(woff_ap + ((size_t)(t * 2 + m) * 64 + lane) * 8);
                oacc[0][m] = __builtin_amdgcn_mfma_f32_16x16x32_f16(A, Bv[0], oacc[0][m], 0, 0, 0);
                oacc[1][m] = __builtin_amdgcn_mfma_f32_16x16x32_f16(A, Bv[1], oacc[1][m], 0, 0, 0);
            }
        }
    }
    if (chh == 0) {
        #pragma unroll
        for (int nt = 0; nt < 2; ++nt)
            #pragma unroll
            for (int m = 0; m < 2; ++m)
                #pragma unroll
                for (int r = 0; r < 4; ++r) {
                    int o = m * 16 + g * 4 + r;
                    if (o < 18) {
                        int pxln = pxg * 32 + nt * 16 + l15;
                        float v = oacc[nt][m][r] + b_off[o];
                        offsm[o * 65 + pxln] = fminf(fmaxf(v, -1.f), 1.f);
                    }
                }
    }
    __syncthreads();

    // ---------------- phase 1: deformable conv, K split by chh ------------
    unsigned co = (unsigned)((chh * 4 + g) * 16);
    f32x4 acc[2][4];                                     // [nt][m]
    {
        f32x4 z = {0.f, 0.f, 0.f, 0.f};
        #pragma unroll
        for (int nt = 0; nt < 2; ++nt)
            #pragma unroll
            for (int m = 0; m < 4; ++m) acc[nt][m] = z;
    }
    #pragma unroll
    for (int kk = 0; kk < 9; ++kk) {
        int ky = kk / 3 - 1, kx = kk - (kk / 3) * 3 - 1;
        int t = kk * 2 + chh;
        f16x8 Bv[2];
        #pragma unroll
        for (int nt = 0; nt < 2; ++nt) {
            int pxln = pxg * 32 + nt * 16 + l15;
            float dy = offsm[(2 * kk) * 65 + pxln];
            float dx = offsm[(2 * kk + 1) * 65 + pxln];
            float py = (float)(h + ky) + dy;
            float pxf = (float)(s + pxln + kx) + dx;
            float y0f = floorf(py), x0f = floorf(pxf);
            float ly = py - y0f, lx = pxf - x0f;
            int y0 = (int)y0f, x0 = (int)x0f;
            float vy0 = ((unsigned)y0 < 128u) ? 1.f : 0.f;
            float vy1 = ((unsigned)(y0 + 1) < 128u) ? 1.f : 0.f;
            float vx0 = ((unsigned)x0 < 128u) ? 1.f : 0.f;
            float vx1 = ((unsigned)(x0 + 1) < 128u) ? 1.f : 0.f;
            f16 w0 = (f16)((1.f - ly) * (1.f - lx) * vy0 * vx0);
            f16 w1 = (f16)((1.f - ly) * lx * vy0 * vx1);
            f16 w2 = (f16)(ly * (1.f - lx) * vy1 * vx0);
            f16 w3 = (f16)(ly * lx * vy1 * vx1);
            int yc0 = min(max(y0, 0), 127), yc1 = min(max(y0 + 1, 0), 127);
            int xc0 = min(max(x0, 0), 127), xc1 = min(max(x0 + 1, 0), 127);
            int ry0 = yc0 - (h - 2), ry1 = yc1 - (h - 2);
            int cx0 = xc0 - (s - 2), cx1 = xc1 - (s - 2);
            unsigned s0 = co ^ (((unsigned)cx0 & 7u) << 4);
            unsigned s1 = co ^ (((unsigned)cx1 & 7u) << 4);
            f16x8 c00 = *(const f16x8*)(band + (ry0 * 69 + cx0) * 128 + s0);
            f16x8 c01 = *(const f16x8*)(band + (ry0 * 69 + cx1) * 128 + s1);
            f16x8 c10 = *(const f16x8*)(band + (ry1 * 69 + cx0) * 128 + s0);
            f16x8 c11 = *(const f16x8*)(band + (ry1 * 69 + cx1) * 128 + s1);
            Bv[nt] = c00 * w0 + c01 * w1 + c10 * w2 + c11 * w3;
        }
        #pragma unroll
        for (int m = 0; m < 4; ++m) {
            f16x8 A = *(const f16x8*)(wdef_ap + ((size_t)(t * 4 + m) * 64 + lane) * 8);
            acc[0][m] = __builtin_amdgcn_mfma_f32_16x16x32_f16(A, Bv[0], acc[0][m], 0, 0, 0);
            acc[1][m] = __builtin_amdgcn_mfma_f32_16x16x32_f16(A, Bv[1], acc[1][m], 0, 0, 0);
        }
    }

    __syncthreads();                                   // band reads done -> red1 safe
    if (chh == 1) {
        #pragma unroll
        for (int nt = 0; nt < 2; ++nt)
            #pragma unroll
            for (int m = 0; m < 4; ++m)
                #pragma unroll
                for (int r = 0; r < 4; ++r) {
                    int o = m * 16 + g * 4 + r;
                    int pxln = pxg * 32 + nt * 16 + l15;
                    red1[o * 65 + pxln] = acc[nt][m][r];
                }
    }
    __syncthreads();
    if (chh == 0) {
        #pragma unroll
        for (int nt = 0; nt < 2; ++nt)
            #pragma unroll
            for (int m = 0; m < 4; ++m)
                #pragma unroll
                for (int r = 0; r < 4; ++r) {
                    int o = m * 16 + g * 4 + r;
                    int pxln = pxg * 32 + nt * 16 + l15;
                    float v = acc[nt][m][r] + red1[o * 65 + pxln] + b_def[o];
                    out[(size_t)(b * 64 + o) * HWB + h * 128 + s + pxln] = v;
                }
    }
}

extern "C" void kernel_launch(void* const* d_in, const int* in_sizes, int n_in,
                              void* d_out, int out_size, void* d_ws, size_t ws_size,
                              hipStream_t stream) {
    const float* x     = (const float*)d_in[0];
    const float* w_off = (const float*)d_in[1];
    const float* b_off = (const float*)d_in[2];
    const float* w_def = (const float*)d_in[3];
    const float* b_def = (const float*)d_in[4];
    float* out = (float*)d_out;

    char* wsb = (char*)d_ws;
    f16* wdef_ap = (f16*)wsb;                    // 73728 B
    f16* woff_ap = (f16*)(wsb + 73728);          // 36864 B
    f16* xt      = (f16*)(wsb + 110592);         // NHWC f16

    if (ws_size >= (size_t)110592 + 8388608) {
        // single shot: prep + all-batch transpose merged, then fused kernel
        k_xprep<<<256, 256, 0, stream>>>(x, xt, w_off, w_def, wdef_ap, woff_ap);
        k_fused<<<1024, 256, 0, stream>>>(xt, woff_ap, b_off, wdef_ap, b_def, out, 0);
    } else {
        // batch-sliced fallback (2.1 MB slice, stream-ordered)
        k_prep<<<216, 256, 0, stream>>>(w_off, w_def, wdef_ap, woff_ap);
        for (int b = 0; b < 4; ++b) {
            k_xpose<<<64, 256, 0, stream>>>(x + (size_t)b * 64 * HWB, xt);
            k_fused<<<256, 256, 0, stream>>>(xt, woff_ap, b_off, wdef_ap, b_def, out, b);
        }
    }
}